// Round 1
// baseline (1316.149 us; speedup 1.0000x reference)
//
#include <hip/hip_runtime.h>
#include <cstdint>

#define NA 20000
#define NE 80000

// per-l offsets (in floats) inside h / pooled / d_out buffers (atom-major, [n][i][j][c])
constexpr int HOFFc[4]   = {0, 2560000, 5120000, 10880000};
// packed rbm layout per edge: rbm0[128] rbm1[96] rbm2[64] rbm3[32]  (320 total)
constexpr int RBMOFFc[4] = {0, 128, 224, 288};
// global q (0..15) -> which l' the sh/rbm row comes from
constexpr int QLPc[16]   = {0,1,1,1,2,2,2,2,2,3,3,3,3,3,3,3};

// ---------------- Kernel 1: EquivariantRMSNorm + linear_in -> h ----------------
// grid (5000, 4), block 256. One wave per atom; l = blockIdx.y.
__global__ __launch_bounds__(256)
void k_norm_in(const float* __restrict__ f0, const float* __restrict__ f1,
               const float* __restrict__ f2, const float* __restrict__ f3,
               const float* __restrict__ gammas, const float* __restrict__ Win,
               float* __restrict__ h)
{
    const int l = blockIdx.y;
    const int S = (l < 2) ? 4 : ((l == 2) ? 9 : 16);
    const float* fsel = (l == 0) ? f0 : ((l == 1) ? f1 : ((l == 2) ? f2 : f3));
    float* hb = h + HOFFc[l];

    __shared__ float s_win[1024];
    __shared__ float s_g[32];
    __shared__ float s_fn[4][16][32];

    const int t = threadIdx.x;
    for (int i = t; i < 1024; i += 256) s_win[i] = Win[l * 1024 + i];
    if (t < 32) s_g[t] = gammas[l * 32 + t];
    __syncthreads();

    const int w = t >> 6, lane = t & 63, c = lane & 31, hlf = lane >> 5;
    const int n = blockIdx.x * 4 + w;
    const float* fp = fsel + (size_t)n * S * 32;

    // per-channel sum of squares over spatial entries (halves split spatial, combine via shfl)
    float ss = 0.f;
    for (int s = hlf; s < S; s += 2) { float v = fp[s * 32 + c]; ss += v * v; }
    ss += __shfl_xor(ss, 32);
    const float scale = s_g[c] * rsqrtf(ss / (float)S + 1e-6f);

    for (int s = hlf; s < S; s += 2) s_fn[w][s][c] = fp[s * 32 + c] * scale;
    __syncthreads();

    float* hp = hb + (size_t)n * S * 32;
    for (int s = hlf; s < S; s += 2) {
        float acc = 0.f;
        #pragma unroll
        for (int ff = 0; ff < 32; ff++) acc += s_fn[w][s][ff] * s_win[ff * 32 + c];
        hp[s * 32 + c] = acc;
    }
}

// ---------------- phase A helper: hidden = silu(rb@A); rbm = hidden@B ----------------
template<int K>
__device__ __forceinline__ void phaseA(int t, const float* __restrict__ Ap,
                                       const float* __restrict__ Bp,
                                       const float (* __restrict__ s_rb_l)[32],
                                       float (* __restrict__ s_hid)[128],
                                       float (* __restrict__ s_rbm)[320], int rbmoff)
{
    const int e  = t >> 4;         // 0..15 edge within tile
    const int j0 = (t & 15) * 8;   // 8 hidden cols per thread
    float acc[8] = {0.f,0.f,0.f,0.f,0.f,0.f,0.f,0.f};
    const float* Arow = Ap + j0;
    #pragma unroll 4
    for (int k = 0; k < 32; k++) {
        const float r = s_rb_l[e][k];
        const float4 a0 = *reinterpret_cast<const float4*>(Arow + k * 128);
        const float4 a1 = *reinterpret_cast<const float4*>(Arow + k * 128 + 4);
        acc[0] += r * a0.x; acc[1] += r * a0.y; acc[2] += r * a0.z; acc[3] += r * a0.w;
        acc[4] += r * a1.x; acc[5] += r * a1.y; acc[6] += r * a1.z; acc[7] += r * a1.w;
    }
    __syncthreads();   // previous iteration's readers of s_hid are done
    #pragma unroll
    for (int u = 0; u < 8; u++) {
        const float x = acc[u];
        s_hid[e][j0 + u] = x / (1.f + __expf(-x));   // silu
    }
    __syncthreads();

    constexpr int W = K / 16;          // 8,6,4,2 output cols per thread
    const int c0 = (t & 15) * W;
    float accb[W] = {};
    const float* Bb = Bp + c0;
    #pragma unroll 2
    for (int j = 0; j < 128; j++) {
        const float hv = s_hid[e][j];
        #pragma unroll
        for (int u = 0; u < W; u += 2) {
            const float2 b = *reinterpret_cast<const float2*>(Bb + j * K + u);
            accb[u] += hv * b.x; accb[u + 1] += hv * b.y;
        }
    }
    #pragma unroll
    for (int u = 0; u < W; u++) s_rbm[e][rbmoff + c0 + u] = accb[u];
}

// ---------------- phase B helper: uncouple + gather + TP + atomic scatter ----------------
template<int LOWERV, int P1, int VQ>
__device__ __forceinline__ void tp_group(const float* __restrict__ sU,
                                         const float* __restrict__ she,
                                         const float* __restrict__ rbme,
                                         const float* __restrict__ hL,
                                         float* __restrict__ pL,
                                         int nbr, int ctr, int c)
{
    constexpr int S = P1 * P1;
    float st[VQ];
    #pragma unroll
    for (int q = 0; q < VQ; q++)
        st[q] = she[q] * rbme[RBMOFFc[QLPc[q]] + LOWERV + c];

    float unc[S];
    #pragma unroll
    for (int p = 0; p < S; p++) {
        float a = 0.f;
        #pragma unroll
        for (int q = 0; q < VQ; q++) a += sU[p * S + q] * st[q];
        unc[p] = a;
    }

    const float* hp = hL + (size_t)nbr * (S * 32) + c;
    float hn[S];
    #pragma unroll
    for (int p = 0; p < S; p++) hn[p] = hp[p * 32];

    float* pp = pL + (size_t)ctr * (S * 32) + c;
    #pragma unroll
    for (int i = 0; i < P1; i++) {
        #pragma unroll
        for (int k = 0; k < P1; k++) {
            float m = 0.f;
            #pragma unroll
            for (int j = 0; j < P1; j++) m += unc[i * P1 + j] * hn[j * P1 + k];
            atomicAdd(pp + (i * P1 + k) * 32, m);
        }
    }
}

// ---------------- Kernel 2: per-edge radial MLP + uncouple + TP + scatter ----------------
// grid 5000, block 256, 16 edges per block.
__global__ __launch_bounds__(256)
void k_edge(const float* __restrict__ rb,
            const float* __restrict__ sh0, const float* __restrict__ sh1,
            const float* __restrict__ sh2, const float* __restrict__ sh3,
            const float* __restrict__ U1, const float* __restrict__ U2,
            const float* __restrict__ U3, const float* __restrict__ A,
            const float* __restrict__ B0, const float* __restrict__ B1,
            const float* __restrict__ B2, const float* __restrict__ B3,
            const int* __restrict__ centers, const int* __restrict__ neighbors,
            const float* __restrict__ h, float* __restrict__ pooled)
{
    __shared__ float s_rb[4][16][32];   // 8 KB
    __shared__ float s_hid[16][128];    // 8 KB (reused per l)
    __shared__ float s_rbm[16][320];    // 20 KB
    __shared__ float s_sh[16][16];      // 1 KB  (q-packed sh values)
    __shared__ float s_U[353];          // U3[256] U2[81] U1[16], pre-scaled by 1/sqrt(P+1)
    __shared__ int   s_nbr[16];
    __shared__ int   s_ctr[16];

    const int t  = threadIdx.x;
    const int e0 = blockIdx.x * 16;

    // stage rb tiles (contiguous per l)
    for (int i = t; i < 2048; i += 256)
        (&s_rb[0][0][0])[i] = rb[(i >> 9) * (NE * 32) + e0 * 32 + (i & 511)];
    // stage sh, q-packed: [0]=sh0, [1..3]=sh1, [4..8]=sh2, [9..15]=sh3
    {
        const int e = t >> 4, q = t & 15, ge = e0 + e;
        float v;
        if (q == 0)      v = sh0[ge];
        else if (q < 4)  v = sh1[ge * 3 + (q - 1)];
        else if (q < 9)  v = sh2[ge * 5 + (q - 4)];
        else             v = sh3[ge * 7 + (q - 9)];
        s_sh[e][q] = v;
    }
    // stage U matrices, folding in the 1/sqrt(P+1) of the TP
    for (int i = t; i < 353; i += 256) {
        float v;
        if (i < 256)      v = U3[i]       * 0.5f;                    // l=3: /sqrt(4)
        else if (i < 337) v = U2[i - 256] * 0.57735026918962576f;    // l=2: /sqrt(3)
        else              v = U1[i - 337] * 0.70710678118654752f;    // l=0,1: /sqrt(2)
        s_U[i] = v;
    }
    if (t < 16) { s_nbr[t] = neighbors[e0 + t]; s_ctr[t] = centers[e0 + t]; }
    __syncthreads();

    // ---- phase A: radial MLP per l ----
    phaseA<128>(t, A,         B0, s_rb[0], s_hid, s_rbm, 0);
    phaseA< 96>(t, A +  4096, B1, s_rb[1], s_hid, s_rbm, 128);
    phaseA< 64>(t, A +  8192, B2, s_rb[2], s_hid, s_rbm, 224);
    phaseA< 32>(t, A + 12288, B3, s_rb[3], s_hid, s_rbm, 288);
    __syncthreads();

    // ---- phase B: per (edge, channel) ----
    const int ch = t & 31;
    #pragma unroll
    for (int eb = 0; eb < 16; eb += 8) {
        const int ee  = eb + (t >> 5);
        const int nbr = s_nbr[ee], ctr = s_ctr[ee];
        tp_group<96, 2,  1>(s_U + 337, s_sh[ee], s_rbm[ee], h,            pooled,            nbr, ctr, ch);
        tp_group<64, 2,  4>(s_U + 337, s_sh[ee], s_rbm[ee], h +  2560000, pooled +  2560000, nbr, ctr, ch);
        tp_group<32, 3,  9>(s_U + 256, s_sh[ee], s_rbm[ee], h +  5120000, pooled +  5120000, nbr, ctr, ch);
        tp_group< 0, 4, 16>(s_U,       s_sh[ee], s_rbm[ee], h + 10880000, pooled + 10880000, nbr, ctr, ch);
    }
}

// ---------------- Kernel 3: out = f + msg_scale * (pooled @ Wout) ----------------
__global__ __launch_bounds__(256)
void k_out(const float* __restrict__ f0, const float* __restrict__ f1,
           const float* __restrict__ f2, const float* __restrict__ f3,
           const float* __restrict__ Wout, const float* __restrict__ msp,
           const float* __restrict__ pooled, float* __restrict__ out)
{
    const int l = blockIdx.y;
    const int S = (l < 2) ? 4 : ((l == 2) ? 9 : 16);
    const float* fsel = (l == 0) ? f0 : ((l == 1) ? f1 : ((l == 2) ? f2 : f3));

    __shared__ float s_w[1024];
    __shared__ float s_p[4][16][32];

    const int t = threadIdx.x;
    for (int i = t; i < 1024; i += 256) s_w[i] = Wout[l * 1024 + i];
    __syncthreads();

    const float ms = *msp;
    const int w = t >> 6, lane = t & 63, c = lane & 31, hlf = lane >> 5;
    const int n = blockIdx.x * 4 + w;

    const float* pp = pooled + HOFFc[l] + (size_t)n * S * 32;
    for (int s = hlf; s < S; s += 2) s_p[w][s][c] = pp[s * 32 + c];
    __syncthreads();

    const float* fp = fsel + (size_t)n * S * 32;
    float* op = out + HOFFc[l] + (size_t)n * S * 32;
    for (int s = hlf; s < S; s += 2) {
        float acc = 0.f;
        #pragma unroll
        for (int ff = 0; ff < 32; ff++) acc += s_p[w][s][ff] * s_w[ff * 32 + c];
        op[s * 32 + c] = fp[s * 32 + c] + ms * acc;
    }
}

extern "C" void kernel_launch(void* const* d_in, const int* in_sizes, int n_in,
                              void* d_out, int out_size, void* d_ws, size_t ws_size,
                              hipStream_t stream)
{
    (void)in_sizes; (void)n_in; (void)out_size;

    const float* rb     = (const float*)d_in[0];
    const float* sh0    = (const float*)d_in[1];
    const float* sh1    = (const float*)d_in[2];
    const float* sh2    = (const float*)d_in[3];
    const float* sh3    = (const float*)d_in[4];
    const float* f0     = (const float*)d_in[5];
    const float* f1     = (const float*)d_in[6];
    const float* f2     = (const float*)d_in[7];
    const float* f3     = (const float*)d_in[8];
    const float* U1     = (const float*)d_in[9];
    const float* U2     = (const float*)d_in[10];
    const float* U3     = (const float*)d_in[11];
    const float* gammas = (const float*)d_in[12];
    const float* Win    = (const float*)d_in[13];
    const float* Wout   = (const float*)d_in[14];
    const float* A      = (const float*)d_in[15];
    const float* B0     = (const float*)d_in[16];
    const float* B1     = (const float*)d_in[17];
    const float* B2     = (const float*)d_in[18];
    const float* B3     = (const float*)d_in[19];
    const float* msp    = (const float*)d_in[20];
    const int* centers   = (const int*)d_in[21];
    const int* neighbors = (const int*)d_in[22];

    // ws layout: h [21.12M floats] | pooled [21.12M floats]  => 168.96 MB
    const size_t needed = (size_t)2 * 21120000 * sizeof(float);
    if (ws_size < needed) return;  // fail loudly (output stays poisoned)

    float* h      = (float*)d_ws;
    float* pooled = h + 21120000;

    hipMemsetAsync(pooled, 0, (size_t)21120000 * sizeof(float), stream);

    dim3 gA(5000, 4);
    k_norm_in<<<gA, 256, 0, stream>>>(f0, f1, f2, f3, gammas, Win, h);
    k_edge<<<5000, 256, 0, stream>>>(rb, sh0, sh1, sh2, sh3, U1, U2, U3, A,
                                     B0, B1, B2, B3, centers, neighbors, h, pooled);
    k_out<<<gA, 256, 0, stream>>>(f0, f1, f2, f3, Wout, msp, pooled, (float*)d_out);
}